// Round 4
// baseline (100400.128 us; speedup 1.0000x reference)
//
#include <hip/hip_runtime.h>
#include <stdint.h>

typedef unsigned int uint32;
typedef unsigned long long uint64;

#define T_SEQ 8192
#define NWG_L 128
#define BLK   320          // 4 compute waves + 1 relay wave

// LDS byte offsets (one layout for both layers; L0 leaves a hole in W region)
#define OFF_W     0        // L0: Whh0 32x2048B @0 ; L1: concat 32x4096B @0
#define OFF_WIH0  65536    // L0 only: Wih0 32x608B
#define OFF_BIAS  131072   // 32 f32
#define OFF_H1    131200   // f32 [2][1024]  (spread layout)
#define OFF_H2    139392   // f32 [2][1024]  (L1 only)
#define OFF_FLAGA 147584
#define OFF_FLAGB 147648
#define OFF_CNT   147712
#define LDS_BYTES 147776

// ---------------- device helpers ----------------
__device__ __forceinline__ float bflo(uint32 u){ return __uint_as_float(u << 16); }
__device__ __forceinline__ float bfhi(uint32 u){ return __uint_as_float(u & 0xffff0000u); }

__device__ __forceinline__ unsigned short f2bf(float f){
  uint32 u = __float_as_uint(f);
  u += 0x7fffu + ((u >> 16) & 1u);
  return (unsigned short)(u >> 16);
}

__device__ __forceinline__ void mac8(float& a, uint4 w,
    float h0,float h1,float h2,float h3,float h4,float h5,float h6,float h7){
  a = fmaf(bflo(w.x), h0, a); a = fmaf(bfhi(w.x), h1, a);
  a = fmaf(bflo(w.y), h2, a); a = fmaf(bfhi(w.y), h3, a);
  a = fmaf(bflo(w.z), h4, a); a = fmaf(bfhi(w.z), h5, a);
  a = fmaf(bflo(w.w), h6, a); a = fmaf(bfhi(w.w), h7, a);
}

__device__ __forceinline__ uint64 ald64(const uint64* p){
  return __hip_atomic_load(p, __ATOMIC_RELAXED, __HIP_MEMORY_SCOPE_AGENT);
}
__device__ __forceinline__ void ast64(uint64* p, uint64 v){
  __hip_atomic_store(p, v, __ATOMIC_RELAXED, __HIP_MEMORY_SCOPE_AGENT);
}
__device__ __forceinline__ uint32 ald32(const uint32* p){
  return __hip_atomic_load(p, __ATOMIC_RELAXED, __HIP_MEMORY_SCOPE_AGENT);
}
__device__ __forceinline__ void ast32(uint32* p, uint32 v){
  __hip_atomic_store(p, v, __ATOMIC_RELAXED, __HIP_MEMORY_SCOPE_AGENT);
}
__device__ __forceinline__ float val_of(uint64 w){ return __uint_as_float((uint32)(w >> 32)); }

// LDS flag helpers (workgroup scope)
__device__ __forceinline__ void lds_wait_ge(uint32* p, uint32 tgt){
  uint32 g = 0;
  while (__hip_atomic_load(p, __ATOMIC_ACQUIRE, __HIP_MEMORY_SCOPE_WORKGROUP) < tgt) {
    __builtin_amdgcn_s_sleep(1);
    if (++g > 20000000u) break;
  }
}
__device__ __forceinline__ void lds_store_rel(uint32* p, uint32 v){
  __hip_atomic_store(p, v, __ATOMIC_RELEASE, __HIP_MEMORY_SCOPE_WORKGROUP);
}
__device__ __forceinline__ void lds_add_rel(uint32* p){
  __hip_atomic_fetch_add(p, 1u, __ATOMIC_RELEASE, __HIP_MEMORY_SCOPE_WORKGROUP);
}

// Relay: gather 1024 tagged words (lane c owns words c*16..+15), retrying only
// missing words, then scatter values into LDS spread layout: word u -> (u&15)*64+(u>>4).
__device__ __forceinline__ void relay_gather(const uint64* base, uint32 want,
                                             float* dst, int c){
  uint64 up[16];
  uint32 mask = 0, guard = 0;
  for (;;) {
    #pragma unroll
    for (int k = 0; k < 16; ++k) if (!((mask >> k) & 1u)) up[k] = ald64(base + k);
    uint32 m = mask;
    #pragma unroll
    for (int k = 0; k < 16; ++k) if ((uint32)up[k] == want) m |= (1u << k);
    mask = m;
    if (__all(mask == 0xffffu)) break;
    if (++guard > 3000000u) break;         // bug -> garbage, not hang
    __builtin_amdgcn_s_sleep(1);
  }
  #pragma unroll
  for (int k = 0; k < 16; ++k) {
    int u = c * 16 + k;                    // u&15 == k  ->  word k*64+c
    dst[(k << 6) + c] = val_of(up[k]);
  }
}

// ---------------- persistent 2-layer LSTM ----------------
// 256 WGs x 320 thr (1 WG/CU). WG 0..127: layer0 (8 units); 128..255: layer1.
// Wave 4 = relay: polls rings (agent scope), fans out h into LDS. Waves 0..3 =
// compute: wave w owns units 2w,2w+1 (rows g*8+2w+j), no intra-step barriers.
// Handshakes: flagA/flagB (relay->compute, monotonic step values), cnt
// (compute->relay, 4 per step) gate LDS double buffers. Publish: tagged
// (fp32<<32)|(t+1) relaxed agent 8B atomics into h1 ring (16) / h2 ring (4).
// L0 overwrite of h1 gen t-16 gated by L1 progress watermark prog >= t-12.
extern "C" __global__ void __launch_bounds__(BLK)
lstm_persistent(const float* __restrict__ quote,
                const float* __restrict__ Wih0, const float* __restrict__ Whh0,
                const float* __restrict__ bih0, const float* __restrict__ bhh0,
                const float* __restrict__ Wih1, const float* __restrict__ Whh1,
                const float* __restrict__ bih1, const float* __restrict__ bhh1,
                uint64* __restrict__ h1r, uint64* __restrict__ h2r,
                uint32* __restrict__ prog, float* __restrict__ h2last)
{
  extern __shared__ char smem[];
  float*  biasL = (float*)(smem + OFF_BIAS);
  float*  bufH1 = (float*)(smem + OFF_H1);
  float*  bufH2 = (float*)(smem + OFF_H2);
  uint32* flagA = (uint32*)(smem + OFF_FLAGA);
  uint32* flagB = (uint32*)(smem + OFF_FLAGB);
  uint32* cntp  = (uint32*)(smem + OFF_CNT);

  const int tid = threadIdx.x;
  const int wv  = tid >> 6;          // 0..4
  const int c   = tid & 63;
  const int wg  = blockIdx.x;
  const bool isL1 = (wg >= NWG_L);
  const int lwg = isL1 ? (wg - NWG_L) : wg;
  const int unit_base = lwg * 8;

  // ---- one-time weight fill: fp32 global -> bf16 LDS (piece-interleaved) ----
  if (!isL1) {
    for (int gi = tid; gi < 4096; gi += BLK) {           // Whh0: 32 rows x 128 groups
      int r  = gi >> 7;
      int x0 = (gi & 127) << 3;
      int R  = (r >> 3) * 1024 + unit_base + (r & 7);
      const float* s = Whh0 + (size_t)R * 1024 + x0;
      unsigned short* d = (unsigned short*)(smem + r*2048 + ((x0>>3)&1)*1024 + (x0>>4)*16);
      #pragma unroll
      for (int m = 0; m < 8; ++m) d[m] = f2bf(s[m]);
    }
    for (int gi = tid; gi < 1216; gi += BLK) {           // Wih0: 32 rows x 38 groups
      int r  = gi / 38;
      int g  = gi - r * 38;
      int x0 = g << 3;
      int R  = (r >> 3) * 1024 + unit_base + (r & 7);
      unsigned short* d = (unsigned short*)(smem + OFF_WIH0 + r*608 + x0*2);
      #pragma unroll
      for (int m = 0; m < 8; ++m) {
        int x = x0 + m;
        d[m] = f2bf(x < 300 ? Wih0[(size_t)R * 300 + x] : 0.0f);
      }
    }
    if (tid < 32) {
      int R = (tid >> 3) * 1024 + unit_base + (tid & 7);
      biasL[tid] = bih0[R] + bhh0[R];
    }
  } else {
    for (int gi = tid; gi < 8192; gi += BLK) {           // concat: 32 rows x 256 groups
      int r  = gi >> 8;
      int x0 = (gi & 255) << 3;
      int R  = (r >> 3) * 1024 + unit_base + (r & 7);
      const float* s = (x0 < 1024) ? (Wih1 + (size_t)R*1024 + x0)
                                   : (Whh1 + (size_t)R*1024 + (x0 - 1024));
      int p  = x0 >> 9;
      int cs = (x0 & 511) >> 3;
      unsigned short* d = (unsigned short*)(smem + r*4096 + p*1024 + cs*16);
      #pragma unroll
      for (int m = 0; m < 8; ++m) d[m] = f2bf(s[m]);
    }
    if (tid < 32) {
      int R = (tid >> 3) * 1024 + unit_base + (tid & 7);
      biasL[tid] = bih1[R] + bhh1[R];
    }
  }
  if (tid == 0) { *flagA = 0; *flagB = 0; *cntp = 0; }
  __syncthreads();

  if (wv == 4) {
    // ======================= RELAY WAVE =======================
    for (int t = 0; t < T_SEQ; ++t) {
      if (t >= 2) lds_wait_ge(cntp, 4u * (uint32)(t - 1));   // buffer t&1 free?
      if (!isL1) {
        if (t > 0) {
          relay_gather(h1r + (size_t)((t-1) & 15) * 1024 + c*16, (uint32)t,
                       bufH1 + (t & 1) * 1024, c);
          if (c == 0) lds_store_rel(flagA, (uint32)t);
        }
      } else {
        if (t > 0) {
          relay_gather(h2r + (size_t)((t-1) & 3) * 1024 + c*16, (uint32)t,
                       bufH2 + (t & 1) * 1024, c);
          if (c == 0) lds_store_rel(flagA, (uint32)t);
        }
        relay_gather(h1r + (size_t)(t & 15) * 1024 + c*16, (uint32)(t + 1),
                     bufH1 + (t & 1) * 1024, c);
        if (c == 0) lds_store_rel(flagB, (uint32)(t + 1));
      }
    }
  } else if (!isL1) {
    // ======================= L0 COMPUTE WAVE (units 2wv, 2wv+1) =======================
    float cstA = 0.0f, cstB = 0.0f;
    uint32 prog_seen = 0;
    float xv[8];
    {
      int x0 = c << 3;
      #pragma unroll
      for (int m = 0; m < 8; ++m)
        xv[m] = (c < 38 && x0 + m < 300) ? quote[x0 + m] : 0.0f;
    }
    for (int t = 0; t < T_SEQ; ++t) {
      float acc[8];
      #pragma unroll
      for (int i = 0; i < 8; ++i) acc[i] = 0.0f;

      // x-part (prefetched registers), rows r = g*8 + 2wv + j
      if (c < 38) {
        #pragma unroll
        for (int g = 0; g < 4; ++g)
          #pragma unroll
          for (int j = 0; j < 2; ++j) {
            int r = g*8 + 2*wv + j;
            uint4 w = *(const uint4*)(smem + OFF_WIH0 + r*608 + (c << 4));
            mac8(acc[g*2+j], w, xv[0],xv[1],xv[2],xv[3],xv[4],xv[5],xv[6],xv[7]);
          }
      }
      // prefetch next x row (hidden under flag wait + h-mac)
      float xn[8];
      if (t + 1 < T_SEQ) {
        int x0 = c << 3;
        const float* xr = quote + (size_t)(t + 1) * 300;
        #pragma unroll
        for (int m = 0; m < 8; ++m)
          xn[m] = (c < 38 && x0 + m < 300) ? xr[x0 + m] : 0.0f;
      } else {
        #pragma unroll
        for (int m = 0; m < 8; ++m) xn[m] = 0.0f;
      }

      if (t > 0) {
        lds_wait_ge(flagA, (uint32)t);
        float hv[16];
        const float* hb = bufH1 + (t & 1) * 1024;
        #pragma unroll
        for (int k = 0; k < 16; ++k) hv[k] = hb[(k << 6) + c];   // spread(c*16+k)
        #pragma unroll
        for (int g = 0; g < 4; ++g)
          #pragma unroll
          for (int j = 0; j < 2; ++j) {
            int r = g*8 + 2*wv + j;
            const char* rowb = smem + r*2048;
            uint4 w0 = *(const uint4*)(rowb + (c << 4));
            uint4 w1 = *(const uint4*)(rowb + 1024 + (c << 4));
            mac8(acc[g*2+j], w0, hv[0],hv[1],hv[2],hv[3],hv[4],hv[5],hv[6],hv[7]);
            mac8(acc[g*2+j], w1, hv[8],hv[9],hv[10],hv[11],hv[12],hv[13],hv[14],hv[15]);
          }
      }
      if (c == 0) lds_add_rel(cntp);

      // full butterfly reduce: every lane ends with the 8 row totals
      #pragma unroll
      for (int i = 0; i < 8; ++i) {
        #pragma unroll
        for (int m = 1; m < 64; m <<= 1) acc[i] += __shfl_xor(acc[i], m);
      }
      // gates (lane-uniform), units A=2wv, B=2wv+1
      float gA0 = acc[0] + biasL[0*8 + 2*wv], gA1 = acc[2] + biasL[1*8 + 2*wv];
      float gA2 = acc[4] + biasL[2*8 + 2*wv], gA3 = acc[6] + biasL[3*8 + 2*wv];
      float iA = 1.0f/(1.0f+expf(-gA0)), fA = 1.0f/(1.0f+expf(-gA1));
      float gA = tanhf(gA2),             oA = 1.0f/(1.0f+expf(-gA3));
      cstA = fA*cstA + iA*gA;
      float hA = oA * tanhf(cstA);
      float gB0 = acc[1] + biasL[0*8 + 2*wv+1], gB1 = acc[3] + biasL[1*8 + 2*wv+1];
      float gB2 = acc[5] + biasL[2*8 + 2*wv+1], gB3 = acc[7] + biasL[3*8 + 2*wv+1];
      float iB = 1.0f/(1.0f+expf(-gB0)), fB = 1.0f/(1.0f+expf(-gB1));
      float gB = tanhf(gB2),             oB = 1.0f/(1.0f+expf(-gB3));
      cstB = fB*cstB + iB*gB;
      float hB = oB * tanhf(cstB);

      if (c == 0) {
        if ((int)prog_seen < t - 12) {     // ring-overwrite back-pressure (rarely taken)
          uint32 guard = 0;
          for (;;) {
            uint32 p = ald32(prog);
            if ((int)p >= t - 12) { prog_seen = p; break; }
            __builtin_amdgcn_s_sleep(2);
            if (++guard > 20000000u) break;
          }
        }
        uint64* slot = h1r + (size_t)(t & 15) * 1024 + unit_base + 2*wv;
        ast64(slot,     ((uint64)__float_as_uint(hA) << 32) | (uint32)(t + 1));
        ast64(slot + 1, ((uint64)__float_as_uint(hB) << 32) | (uint32)(t + 1));
      }
      #pragma unroll
      for (int m = 0; m < 8; ++m) xv[m] = xn[m];
    }
  } else {
    // ======================= L1 COMPUTE WAVE (units 2wv, 2wv+1) =======================
    float cstA = 0.0f, cstB = 0.0f;
    for (int t = 0; t < T_SEQ; ++t) {
      float acc[8];
      #pragma unroll
      for (int i = 0; i < 8; ++i) acc[i] = 0.0f;

      // phase A: Whh1 * h2[t-1]  (pieces 2,3)
      if (t > 0) {
        lds_wait_ge(flagA, (uint32)t);
        float hv[16];
        const float* hb = bufH2 + (t & 1) * 1024;
        #pragma unroll
        for (int k = 0; k < 8; ++k) {
          int u  = (c << 3) + k;
          int u2 = 512 + (c << 3) + k;
          hv[k]     = hb[((u  & 15) << 6) + (u  >> 4)];
          hv[8 + k] = hb[((u2 & 15) << 6) + (u2 >> 4)];
        }
        #pragma unroll
        for (int g = 0; g < 4; ++g)
          #pragma unroll
          for (int j = 0; j < 2; ++j) {
            int r = g*8 + 2*wv + j;
            const char* rowb = smem + r*4096;
            uint4 w2 = *(const uint4*)(rowb + 2048 + (c << 4));
            uint4 w3 = *(const uint4*)(rowb + 3072 + (c << 4));
            mac8(acc[g*2+j], w2, hv[0],hv[1],hv[2],hv[3],hv[4],hv[5],hv[6],hv[7]);
            mac8(acc[g*2+j], w3, hv[8],hv[9],hv[10],hv[11],hv[12],hv[13],hv[14],hv[15]);
          }
      }
      // phase B: Wih1 * h1[t]  (pieces 0,1)
      {
        lds_wait_ge(flagB, (uint32)(t + 1));
        float hv[16];
        const float* hb = bufH1 + (t & 1) * 1024;
        #pragma unroll
        for (int k = 0; k < 8; ++k) {
          int u  = (c << 3) + k;
          int u2 = 512 + (c << 3) + k;
          hv[k]     = hb[((u  & 15) << 6) + (u  >> 4)];
          hv[8 + k] = hb[((u2 & 15) << 6) + (u2 >> 4)];
        }
        #pragma unroll
        for (int g = 0; g < 4; ++g)
          #pragma unroll
          for (int j = 0; j < 2; ++j) {
            int r = g*8 + 2*wv + j;
            const char* rowb = smem + r*4096;
            uint4 w0 = *(const uint4*)(rowb + (c << 4));
            uint4 w1 = *(const uint4*)(rowb + 1024 + (c << 4));
            mac8(acc[g*2+j], w0, hv[0],hv[1],hv[2],hv[3],hv[4],hv[5],hv[6],hv[7]);
            mac8(acc[g*2+j], w1, hv[8],hv[9],hv[10],hv[11],hv[12],hv[13],hv[14],hv[15]);
          }
      }
      if (c == 0) lds_add_rel(cntp);

      #pragma unroll
      for (int i = 0; i < 8; ++i) {
        #pragma unroll
        for (int m = 1; m < 64; m <<= 1) acc[i] += __shfl_xor(acc[i], m);
      }
      float gA0 = acc[0] + biasL[0*8 + 2*wv], gA1 = acc[2] + biasL[1*8 + 2*wv];
      float gA2 = acc[4] + biasL[2*8 + 2*wv], gA3 = acc[6] + biasL[3*8 + 2*wv];
      float iA = 1.0f/(1.0f+expf(-gA0)), fA = 1.0f/(1.0f+expf(-gA1));
      float gA = tanhf(gA2),             oA = 1.0f/(1.0f+expf(-gA3));
      cstA = fA*cstA + iA*gA;
      float hA = oA * tanhf(cstA);
      float gB0 = acc[1] + biasL[0*8 + 2*wv+1], gB1 = acc[3] + biasL[1*8 + 2*wv+1];
      float gB2 = acc[5] + biasL[2*8 + 2*wv+1], gB3 = acc[7] + biasL[3*8 + 2*wv+1];
      float iB = 1.0f/(1.0f+expf(-gB0)), fB = 1.0f/(1.0f+expf(-gB1));
      float gB = tanhf(gB2),             oB = 1.0f/(1.0f+expf(-gB3));
      cstB = fB*cstB + iB*gB;
      float hB = oB * tanhf(cstB);

      if (c == 0) {
        uint64* slot = h2r + (size_t)(t & 3) * 1024 + unit_base + 2*wv;
        ast64(slot,     ((uint64)__float_as_uint(hA) << 32) | (uint32)(t + 1));
        ast64(slot + 1, ((uint64)__float_as_uint(hB) << 32) | (uint32)(t + 1));
        if (t == T_SEQ - 1) {
          h2last[unit_base + 2*wv]     = hA;
          h2last[unit_base + 2*wv + 1] = hB;
        }
        if (lwg == 0 && wv == 0) ast32(prog, (uint32)(t + 1));  // L1 watermark
      }
    }
  }
}

// ---------------- tiny MLP head ----------------
extern "C" __global__ void __launch_bounds__(256)
head_fc(const float* __restrict__ W, const float* __restrict__ b,
        const float* __restrict__ xin, float* __restrict__ y, int n_in)
{
  __shared__ float sred[256];
  const int i = blockIdx.x;
  float p = 0.0f;
  for (int k = threadIdx.x; k < n_in; k += 256)
    p = fmaf(W[(size_t)i * n_in + k], xin[k], p);
  sred[threadIdx.x] = p;
  __syncthreads();
  for (int s = 128; s > 0; s >>= 1) {
    if (threadIdx.x < s) sred[threadIdx.x] += sred[threadIdx.x + s];
    __syncthreads();
  }
  if (threadIdx.x == 0) y[i] = fmaxf(sred[0] + b[i], 0.0f);
}

extern "C" __global__ void __launch_bounds__(64)
head_out(const float* __restrict__ W2, const float* __restrict__ b2,
         const float* __restrict__ y1, float* __restrict__ out)
{
  const int l = threadIdx.x;
  float p0 = 0.0f, p1 = 0.0f, p2 = 0.0f;
  for (int k = l; k < 512; k += 64) {
    float v = y1[k];
    p0 = fmaf(W2[k],        v, p0);
    p1 = fmaf(W2[512 + k],  v, p1);
    p2 = fmaf(W2[1024 + k], v, p2);
  }
  #pragma unroll
  for (int m = 1; m < 64; m <<= 1) {
    p0 += __shfl_xor(p0, m);
    p1 += __shfl_xor(p1, m);
    p2 += __shfl_xor(p2, m);
  }
  if (l == 0) {
    float z0 = p0 + b2[0], z1 = p1 + b2[1], z2 = p2 + b2[2];
    float mx = fmaxf(z0, fmaxf(z1, z2));
    float lse = mx + logf(expf(z0 - mx) + expf(z1 - mx) + expf(z2 - mx));
    out[0] = z0 - lse; out[1] = z1 - lse; out[2] = z2 - lse;
  }
}

// ---------------- host ----------------
extern "C" void kernel_launch(void* const* d_in, const int* in_sizes, int n_in,
                              void* d_out, int out_size, void* d_ws, size_t ws_size,
                              hipStream_t stream)
{
  (void)in_sizes; (void)n_in; (void)out_size; (void)ws_size;
  const float* quote = (const float*)d_in[0];
  const float* Wih0  = (const float*)d_in[1];
  const float* Whh0  = (const float*)d_in[2];
  const float* bih0  = (const float*)d_in[3];
  const float* bhh0  = (const float*)d_in[4];
  const float* Wih1  = (const float*)d_in[5];
  const float* Whh1  = (const float*)d_in[6];
  const float* bih1  = (const float*)d_in[7];
  const float* bhh1  = (const float*)d_in[8];
  const float* W0    = (const float*)d_in[9];
  const float* b0    = (const float*)d_in[10];
  const float* W1    = (const float*)d_in[11];
  const float* b1    = (const float*)d_in[12];
  const float* W2    = (const float*)d_in[13];
  const float* b2    = (const float*)d_in[14];

  char* ws = (char*)d_ws;
  uint64* h1r    = (uint64*)(ws + 0);          // [16][1024] tagged fp32 (128 KB)
  uint64* h2r    = (uint64*)(ws + 131072);     // [4][1024]  tagged fp32 (32 KB)
  uint32* prog   = (uint32*)(ws + 163840);     // L1 progress watermark
  float*  h2last = (float*)(ws + 163968);      // 1024 f32
  float*  y0     = (float*)(ws + 168064);      // 512 f32
  float*  y1     = (float*)(ws + 170112);      // 512 f32

  hipMemsetAsync(ws, 0, 163968, stream);       // rings + watermark zero each call

  hipFuncSetAttribute((const void*)lstm_persistent,
                      hipFuncAttributeMaxDynamicSharedMemorySize, LDS_BYTES);

  void* args[] = { (void*)&quote, (void*)&Wih0, (void*)&Whh0, (void*)&bih0, (void*)&bhh0,
                   (void*)&Wih1, (void*)&Whh1, (void*)&bih1, (void*)&bhh1,
                   (void*)&h1r, (void*)&h2r, (void*)&prog, (void*)&h2last };
  hipLaunchCooperativeKernel((const void*)lstm_persistent, dim3(256), dim3(BLK),
                             args, (uint32)LDS_BYTES, stream);

  head_fc<<<512, 256, 0, stream>>>(W0, b0, h2last, y0, 1024);
  head_fc<<<512, 256, 0, stream>>>(W1, b1, y0, y1, 512);
  head_out<<<1, 64, 0, stream>>>(W2, b2, y1, (float*)d_out);
}

// Round 5
// 64127.930 us; speedup vs baseline: 1.5656x; 1.5656x over previous
//
#include <hip/hip_runtime.h>
#include <stdint.h>

typedef unsigned int uint32;
typedef unsigned long long uint64;

#define T_SEQ 8192
#define NWG_L 128

// LDS byte offsets
#define OFF_RED   131072           // f32 [2][32][8]  (double-buffered)
#define OFF_BIAS  133120           // f32 [32]
#define LDS_BYTES 133248

// ---------------- device helpers ----------------
__device__ __forceinline__ float bflo(uint32 u){ return __uint_as_float(u << 16); }
__device__ __forceinline__ float bfhi(uint32 u){ return __uint_as_float(u & 0xffff0000u); }

__device__ __forceinline__ unsigned short f2bf(float f){
  uint32 u = __float_as_uint(f);
  u += 0x7fffu + ((u >> 16) & 1u);          // round-to-nearest-even
  return (unsigned short)(u >> 16);
}

__device__ __forceinline__ void mac8(float& a, uint4 w,
    float h0,float h1,float h2,float h3,float h4,float h5,float h6,float h7){
  a = fmaf(bflo(w.x), h0, a); a = fmaf(bfhi(w.x), h1, a);
  a = fmaf(bflo(w.y), h2, a); a = fmaf(bfhi(w.y), h3, a);
  a = fmaf(bflo(w.z), h4, a); a = fmaf(bfhi(w.z), h5, a);
  a = fmaf(bflo(w.w), h6, a); a = fmaf(bfhi(w.w), h7, a);
}

__device__ __forceinline__ uint64 ald64(const uint64* p){
  return __hip_atomic_load(p, __ATOMIC_RELAXED, __HIP_MEMORY_SCOPE_AGENT);
}
__device__ __forceinline__ void ast64(uint64* p, uint64 v){
  __hip_atomic_store(p, v, __ATOMIC_RELAXED, __HIP_MEMORY_SCOPE_AGENT);
}
__device__ __forceinline__ uint32 ald32(const uint32* p){
  return __hip_atomic_load(p, __ATOMIC_RELAXED, __HIP_MEMORY_SCOPE_AGENT);
}
__device__ __forceinline__ void ast32(uint32* p, uint32 v){
  __hip_atomic_store(p, v, __ATOMIC_RELAXED, __HIP_MEMORY_SCOPE_AGENT);
}
__device__ __forceinline__ float val_of(uint64 w){ return __uint_as_float((uint32)(w >> 32)); }

// ---------------- persistent 2-layer LSTM, coalesced tagged dataflow ----------------
// 256 WGs x 256 thr (1 WG/CU). WG 0..127: layer0 (8 units each); 128..255: layer1.
// Ring element for unit u lives at index spread(u) = (u&15)*64 + (u>>4), value
// (fp32(h)<<32)|(t+1), ONE relaxed agent 8B atomic. spread() makes consumer polls
// COALESCED: L0 lane c reads ring[k*64+c] == h[c*16+k] (16 x 512B contiguous loads);
// round-3's uncoalesced stride-128B polls (1024 reqs/round/wave) were the detect cost.
// h1 ring depth 16, h2 ring depth 4. Intra-layer WG skew <= 1 (all-to-all coupling).
// L0 overwrite of h1 gen t-16 gated by L1 watermark prog >= t-12.
// LDS: L0: Whh0[32r][2 pieces x 64 x 16B] @0, Wih0[32][608B] @65536
//      L1: concat[Wih1|Whh1][32r][4 pieces x 64 x 16B] @0 (128KB)
//      both: red[2][32][8] @131072, bias[32] @133120
extern "C" __global__ void __launch_bounds__(256)
lstm_persistent(const float* __restrict__ quote,
                const float* __restrict__ Wih0, const float* __restrict__ Whh0,
                const float* __restrict__ bih0, const float* __restrict__ bhh0,
                const float* __restrict__ Wih1, const float* __restrict__ Whh1,
                const float* __restrict__ bih1, const float* __restrict__ bhh1,
                uint64* __restrict__ h1r, uint64* __restrict__ h2r,
                uint32* __restrict__ prog, float* __restrict__ h2last)
{
  extern __shared__ char smem[];
  float* redb  = (float*)(smem + OFF_RED);
  float* biasL = (float*)(smem + OFF_BIAS);

  const int tid = threadIdx.x;
  const int rg  = tid >> 6;
  const int c   = tid & 63;
  const int wg  = blockIdx.x;
  const bool isL1 = (wg >= NWG_L);
  const int lwg = isL1 ? (wg - NWG_L) : wg;
  const int unit_base = lwg * 8;

  // ---- one-time weight fill: fp32 global -> bf16 LDS (piece-interleaved) ----
  if (!isL1) {
    for (int gi = tid; gi < 4096; gi += 256) {           // Whh0: 32 rows x 128 groups
      int r  = gi >> 7;
      int x0 = (gi & 127) << 3;
      int R  = (r >> 3) * 1024 + unit_base + (r & 7);
      const float* s = Whh0 + (size_t)R * 1024 + x0;
      unsigned short* d = (unsigned short*)(smem + r*2048 + ((x0>>3)&1)*1024 + (x0>>4)*16);
      #pragma unroll
      for (int m = 0; m < 8; ++m) d[m] = f2bf(s[m]);
    }
    for (int gi = tid; gi < 1216; gi += 256) {           // Wih0: 32 rows x 38 groups
      int r  = gi / 38;
      int g  = gi - r * 38;
      int x0 = g << 3;
      int R  = (r >> 3) * 1024 + unit_base + (r & 7);
      unsigned short* d = (unsigned short*)(smem + 65536 + r*608 + x0*2);
      #pragma unroll
      for (int m = 0; m < 8; ++m) {
        int x = x0 + m;
        d[m] = f2bf(x < 300 ? Wih0[(size_t)R * 300 + x] : 0.0f);
      }
    }
    if (tid < 32) {
      int R = (tid >> 3) * 1024 + unit_base + (tid & 7);
      biasL[tid] = bih0[R] + bhh0[R];
    }
  } else {
    for (int gi = tid; gi < 8192; gi += 256) {           // concat: 32 rows x 256 groups
      int r  = gi >> 8;
      int x0 = (gi & 255) << 3;                          // concat col 0..2047
      int R  = (r >> 3) * 1024 + unit_base + (r & 7);
      const float* s = (x0 < 1024) ? (Wih1 + (size_t)R*1024 + x0)
                                   : (Whh1 + (size_t)R*1024 + (x0 - 1024));
      int p  = x0 >> 9;
      int cs = (x0 & 511) >> 3;
      unsigned short* d = (unsigned short*)(smem + r*4096 + p*1024 + cs*16);
      #pragma unroll
      for (int m = 0; m < 8; ++m) d[m] = f2bf(s[m]);
    }
    if (tid < 32) {
      int R = (tid >> 3) * 1024 + unit_base + (tid & 7);
      biasL[tid] = bih1[R] + bhh1[R];
    }
  }
  __syncthreads();

  float c_state = 0.0f;       // cell state of unit (tid) for tid<8
  uint32 prog_seen = 0;

  for (int t = 0; t < T_SEQ; ++t) {
    float acc[8];
    #pragma unroll
    for (int i = 0; i < 8; ++i) acc[i] = 0.0f;

    if (!isL1) {
      // ---- issue h1[t-1] loads (coalesced: ring[k*64+c] == h[c*16+k]) ----
      uint64 up[16];
      const uint64* hb = h1r + (size_t)((t-1) & 15) * 1024;
      if (t > 0) {
        #pragma unroll
        for (int k = 0; k < 16; ++k) up[k] = ald64(hb + (k << 6) + c);
      }
      // ---- x-part from LDS (independent of recurrence, hides poll latency) ----
      if (c < 38) {
        float xv[8];
        int x0 = c << 3;
        const float* xr = quote + (size_t)t * 300 + x0;
        #pragma unroll
        for (int m = 0; m < 8; ++m) xv[m] = (x0 + m < 300) ? xr[m] : 0.0f;
        #pragma unroll
        for (int r8 = 0; r8 < 8; ++r8) {
          uint4 w = *(const uint4*)(smem + 65536 + (rg*8 + r8)*608 + (c << 4));
          mac8(acc[r8], w, xv[0],xv[1],xv[2],xv[3],xv[4],xv[5],xv[6],xv[7]);
        }
      }
      if (t > 0) {
        const uint32 want = (uint32)t;
        uint32 guard = 0;
        for (;;) {
          bool ok = true;
          #pragma unroll
          for (int k = 0; k < 16; ++k) ok &= ((uint32)up[k] == want);
          if (__all(ok)) break;
          __builtin_amdgcn_s_sleep(2);
          if (++guard > 20000000u) break;      // deadlock -> garbage, not hang
          #pragma unroll
          for (int k = 0; k < 16; ++k) up[k] = ald64(hb + (k << 6) + c);
        }
        #pragma unroll
        for (int r8 = 0; r8 < 8; ++r8) {
          const char* rowb = smem + (rg*8 + r8)*2048;
          uint4 w0 = *(const uint4*)(rowb + (c << 4));
          uint4 w1 = *(const uint4*)(rowb + 1024 + (c << 4));
          mac8(acc[r8], w0, val_of(up[0]),val_of(up[1]),val_of(up[2]),val_of(up[3]),
                            val_of(up[4]),val_of(up[5]),val_of(up[6]),val_of(up[7]));
          mac8(acc[r8], w1, val_of(up[8]),val_of(up[9]),val_of(up[10]),val_of(up[11]),
                            val_of(up[12]),val_of(up[13]),val_of(up[14]),val_of(up[15]));
        }
      }
    } else {
      // Lane c needs h[c*8+k] and h[512+c*8+k]: ring idx v=((c&1)*8+k)*64+(c>>1), v+32.
      const int vbase = ((c & 1) << 9) + (c >> 1);       // ((c&1)*8)<<6 + (c>>1)
      uint64 ua[16], ub[16];
      const uint64* h2b = h2r + (size_t)((t-1) & 3) * 1024;
      const uint64* h1b = h1r + (size_t)(t & 15) * 1024;
      // issue both phases' loads upfront
      if (t > 0) {
        #pragma unroll
        for (int k = 0; k < 8; ++k) {
          ua[k]   = ald64(h2b + vbase + (k << 6));
          ua[8+k] = ald64(h2b + vbase + (k << 6) + 32);
        }
      }
      #pragma unroll
      for (int k = 0; k < 8; ++k) {
        ub[k]   = ald64(h1b + vbase + (k << 6));
        ub[8+k] = ald64(h1b + vbase + (k << 6) + 32);
      }

      // ---- phase B first: Wih1 * h1[t] (tag t+1; L0 runs ahead -> usually instant) ----
      {
        const uint32 want = (uint32)(t + 1);
        uint32 guard = 0;
        for (;;) {
          bool ok = true;
          #pragma unroll
          for (int k = 0; k < 16; ++k) ok &= ((uint32)ub[k] == want);
          if (__all(ok)) break;
          __builtin_amdgcn_s_sleep(2);
          if (++guard > 20000000u) break;
          #pragma unroll
          for (int k = 0; k < 8; ++k) {
            ub[k]   = ald64(h1b + vbase + (k << 6));
            ub[8+k] = ald64(h1b + vbase + (k << 6) + 32);
          }
        }
        #pragma unroll
        for (int r8 = 0; r8 < 8; ++r8) {       // pieces 0,1
          const char* rowb = smem + (rg*8 + r8)*4096;
          uint4 w0 = *(const uint4*)(rowb + (c << 4));
          uint4 w1 = *(const uint4*)(rowb + 1024 + (c << 4));
          mac8(acc[r8], w0, val_of(ub[0]),val_of(ub[1]),val_of(ub[2]),val_of(ub[3]),
                            val_of(ub[4]),val_of(ub[5]),val_of(ub[6]),val_of(ub[7]));
          mac8(acc[r8], w1, val_of(ub[8]),val_of(ub[9]),val_of(ub[10]),val_of(ub[11]),
                            val_of(ub[12]),val_of(ub[13]),val_of(ub[14]),val_of(ub[15]));
        }
      }
      // ---- phase A: Whh1 * h2[t-1] (tag t; self-layer handoff, partly hidden by B) ----
      if (t > 0) {
        const uint32 want = (uint32)t;
        uint32 guard = 0;
        for (;;) {
          bool ok = true;
          #pragma unroll
          for (int k = 0; k < 16; ++k) ok &= ((uint32)ua[k] == want);
          if (__all(ok)) break;
          __builtin_amdgcn_s_sleep(2);
          if (++guard > 20000000u) break;
          #pragma unroll
          for (int k = 0; k < 8; ++k) {
            ua[k]   = ald64(h2b + vbase + (k << 6));
            ua[8+k] = ald64(h2b + vbase + (k << 6) + 32);
          }
        }
        #pragma unroll
        for (int r8 = 0; r8 < 8; ++r8) {       // pieces 2,3
          const char* rowb = smem + (rg*8 + r8)*4096;
          uint4 w2 = *(const uint4*)(rowb + 2048 + (c << 4));
          uint4 w3 = *(const uint4*)(rowb + 3072 + (c << 4));
          mac8(acc[r8], w2, val_of(ua[0]),val_of(ua[1]),val_of(ua[2]),val_of(ua[3]),
                            val_of(ua[4]),val_of(ua[5]),val_of(ua[6]),val_of(ua[7]));
          mac8(acc[r8], w3, val_of(ua[8]),val_of(ua[9]),val_of(ua[10]),val_of(ua[11]),
                            val_of(ua[12]),val_of(ua[13]),val_of(ua[14]),val_of(ua[15]));
        }
      }
    }

    // ---- reduce -> lanes 0..7 hold the 8 partials per gate row ----
    #pragma unroll
    for (int r8 = 0; r8 < 8; ++r8) {
      acc[r8] += __shfl_xor(acc[r8], 8);
      acc[r8] += __shfl_xor(acc[r8], 16);
      acc[r8] += __shfl_xor(acc[r8], 32);
    }
    float* red = redb + (t & 1) * 256;
    if (c < 8) {
      #pragma unroll
      for (int r8 = 0; r8 < 8; ++r8) red[(rg*8 + r8)*8 + c] = acc[r8];
    }
    __syncthreads();   // single barrier per step (red[] double-buffered)

    // ---- gates, state update, tagged publish (wave 0, lanes 0..7) ----
    if (tid < 8) {
      float gs[4];
      #pragma unroll
      for (int g = 0; g < 4; ++g) {
        const float* rp = red + (g*8 + tid)*8;
        gs[g] = ((rp[0]+rp[1]) + (rp[2]+rp[3])) + ((rp[4]+rp[5]) + (rp[6]+rp[7]))
              + biasL[g*8 + tid];
      }
      float ig = 1.0f / (1.0f + expf(-gs[0]));
      float fg = 1.0f / (1.0f + expf(-gs[1]));
      float gg = tanhf(gs[2]);
      float og = 1.0f / (1.0f + expf(-gs[3]));
      c_state = fg * c_state + ig * gg;
      float h = og * tanhf(c_state);
      const int u = unit_base + tid;
      const int v = ((u & 15) << 6) | (u >> 4);          // spread index
      uint64 pk = ((uint64)__float_as_uint(h) << 32) | (uint32)(t + 1);

      if (!isL1) {
        if ((int)prog_seen < t - 12) {     // ring back-pressure (rarely taken)
          uint32 guard = 0;
          for (;;) {
            uint32 p = ald32(prog);
            if ((int)p >= t - 12) { prog_seen = p; break; }
            __builtin_amdgcn_s_sleep(2);
            if (++guard > 20000000u) break;
          }
        }
        ast64(h1r + (size_t)(t & 15) * 1024 + v, pk);
      } else {
        ast64(h2r + (size_t)(t & 3) * 1024 + v, pk);
        if (t == T_SEQ - 1) h2last[u] = h;
        if (lwg == 0 && tid == 0) ast32(prog, (uint32)(t + 1));
      }
    }
  }
}

// ---------------- tiny MLP head ----------------
extern "C" __global__ void __launch_bounds__(256)
head_fc(const float* __restrict__ W, const float* __restrict__ b,
        const float* __restrict__ xin, float* __restrict__ y, int n_in)
{
  __shared__ float sred[256];
  const int i = blockIdx.x;
  float p = 0.0f;
  for (int k = threadIdx.x; k < n_in; k += 256)
    p = fmaf(W[(size_t)i * n_in + k], xin[k], p);
  sred[threadIdx.x] = p;
  __syncthreads();
  for (int s = 128; s > 0; s >>= 1) {
    if (threadIdx.x < s) sred[threadIdx.x] += sred[threadIdx.x + s];
    __syncthreads();
  }
  if (threadIdx.x == 0) y[i] = fmaxf(sred[0] + b[i], 0.0f);
}

extern "C" __global__ void __launch_bounds__(64)
head_out(const float* __restrict__ W2, const float* __restrict__ b2,
         const float* __restrict__ y1, float* __restrict__ out)
{
  const int l = threadIdx.x;
  float p0 = 0.0f, p1 = 0.0f, p2 = 0.0f;
  for (int k = l; k < 512; k += 64) {
    float v = y1[k];
    p0 = fmaf(W2[k],        v, p0);
    p1 = fmaf(W2[512 + k],  v, p1);
    p2 = fmaf(W2[1024 + k], v, p2);
  }
  #pragma unroll
  for (int m = 1; m < 64; m <<= 1) {
    p0 += __shfl_xor(p0, m);
    p1 += __shfl_xor(p1, m);
    p2 += __shfl_xor(p2, m);
  }
  if (l == 0) {
    float z0 = p0 + b2[0], z1 = p1 + b2[1], z2 = p2 + b2[2];
    float mx = fmaxf(z0, fmaxf(z1, z2));
    float lse = mx + logf(expf(z0 - mx) + expf(z1 - mx) + expf(z2 - mx));
    out[0] = z0 - lse; out[1] = z1 - lse; out[2] = z2 - lse;
  }
}

// ---------------- host ----------------
extern "C" void kernel_launch(void* const* d_in, const int* in_sizes, int n_in,
                              void* d_out, int out_size, void* d_ws, size_t ws_size,
                              hipStream_t stream)
{
  (void)in_sizes; (void)n_in; (void)out_size; (void)ws_size;
  const float* quote = (const float*)d_in[0];
  const float* Wih0  = (const float*)d_in[1];
  const float* Whh0  = (const float*)d_in[2];
  const float* bih0  = (const float*)d_in[3];
  const float* bhh0  = (const float*)d_in[4];
  const float* Wih1  = (const float*)d_in[5];
  const float* Whh1  = (const float*)d_in[6];
  const float* bih1  = (const float*)d_in[7];
  const float* bhh1  = (const float*)d_in[8];
  const float* W0    = (const float*)d_in[9];
  const float* b0    = (const float*)d_in[10];
  const float* W1    = (const float*)d_in[11];
  const float* b1    = (const float*)d_in[12];
  const float* W2    = (const float*)d_in[13];
  const float* b2    = (const float*)d_in[14];

  char* ws = (char*)d_ws;
  uint64* h1r    = (uint64*)(ws + 0);          // [16][1024] tagged fp32 (128 KB)
  uint64* h2r    = (uint64*)(ws + 131072);     // [4][1024]  tagged fp32 (32 KB)
  uint32* prog   = (uint32*)(ws + 163840);     // L1 progress watermark
  float*  h2last = (float*)(ws + 163968);      // 1024 f32
  float*  y0     = (float*)(ws + 168064);      // 512 f32
  float*  y1     = (float*)(ws + 170112);      // 512 f32

  hipMemsetAsync(ws, 0, 163968, stream);       // rings + watermark zero each call

  hipFuncSetAttribute((const void*)lstm_persistent,
                      hipFuncAttributeMaxDynamicSharedMemorySize, LDS_BYTES);

  void* args[] = { (void*)&quote, (void*)&Wih0, (void*)&Whh0, (void*)&bih0, (void*)&bhh0,
                   (void*)&Wih1, (void*)&Whh1, (void*)&bih1, (void*)&bhh1,
                   (void*)&h1r, (void*)&h2r, (void*)&prog, (void*)&h2last };
  hipLaunchCooperativeKernel((const void*)lstm_persistent, dim3(256), dim3(256),
                             args, (uint32)LDS_BYTES, stream);

  head_fc<<<512, 256, 0, stream>>>(W0, b0, h2last, y0, 1024);
  head_fc<<<512, 256, 0, stream>>>(W1, b1, y0, y1, 512);
  head_out<<<1, 64, 0, stream>>>(W2, b2, y1, (float*)d_out);
}